// Round 5
// baseline (7401.453 us; speedup 1.0000x reference)
//
#include <hip/hip_runtime.h>

// ---------------------------------------------------------------------------
// RNN_69526930588180: 3-layer SimpleRNN (tanh), B=256, T=256, D=64, H=512.
//
// Round 5: tag-embedded h exchange. Each h element stored as
//   u32 = (bf16(h) << 16) | tag16,  tag = layer*256 + t + 1.
// Consumers load A-fragments with the PROVEN sc0 sc1 protocol and retry until
// all tags match -> no flags, no atomics, no producer vmcnt wait, and NO
// __syncthreads in the step loop (each wave owns 16 cols end-to-end; proj and
// rec accumulate in the same C-layout registers).
// Partitioning: 128 WGs = 16 batch-groups x 8 col-groups (64 cols/WG, 16/wave).
// Wh/Wx slices live in LDS (128 KB), rotated layout -> 2-way conflicts (free).
// Workspace: 2 tagged seq buffers (134 MB each). Tags are unique across the
// A-buffer reuse (L0: 1..256, L2: 513..768) and differ from 0xAAAA poison.
// ---------------------------------------------------------------------------

typedef unsigned short u16;
typedef unsigned int   u32;

typedef __attribute__((ext_vector_type(8))) short short8;
typedef __attribute__((ext_vector_type(4))) float f32x4;
typedef __attribute__((ext_vector_type(4))) int   i32x4;

#define N_B 256
#define N_T 256
#define N_D 64
#define N_H 512
#define GBg 16   // batch groups
#define CG  8    // col groups
#define BC  16   // rows per batch group
#define WCOLS 64 // cols per WG (16 per wave)

__device__ __forceinline__ u16 f2bf(float f) {
  union { float f; u32 u; } v; v.f = f;
  u32 u = v.u;
  u += 0x7fffu + ((u >> 16) & 1u);   // RNE
  return (u16)(u >> 16);
}
__device__ __forceinline__ float bf2f(u16 h) {
  union { u32 u; float f; } v; v.u = ((u32)h) << 16;
  return v.f;
}
__device__ __forceinline__ short8 ld8(const u16* p) { return *(const short8*)p; }
__device__ __forceinline__ short8 cvt8(const float* p) {
  short8 r;
#pragma unroll
  for (int j = 0; j < 8; ++j) r[j] = (short)f2bf(p[j]);
  return r;
}
// out = (w0>>16) | (w1 & 0xFFFF0000): bytes [w0.2, w0.3, w1.2, w1.3]
__device__ __forceinline__ u32 perm2(u32 w0, u32 w1) {
  return __builtin_amdgcn_perm(w1, w0, 0x07060302u);
}
__device__ __forceinline__ short8 unpack_frag(i32x4 q0, i32x4 q1) {
  union { u32 u[4]; short8 s; } r;
  r.u[0] = perm2((u32)q0[0], (u32)q0[1]);
  r.u[1] = perm2((u32)q0[2], (u32)q0[3]);
  r.u[2] = perm2((u32)q1[0], (u32)q1[1]);
  r.u[3] = perm2((u32)q1[2], (u32)q1[3]);
  return r.s;
}
// tanh(x) = 1 - 2/(exp(2x)+1); clamped (saturated anyway).
__device__ __forceinline__ float fast_tanh(float x) {
  float xc = fminf(fmaxf(x, -9.f), 9.f);
  float e  = __builtin_amdgcn_exp2f(xc * 2.8853900817779268f);
  return 1.f - 2.f * __builtin_amdgcn_rcpf(e + 1.f);
}

// 16 tagged dwordx4 (fragments kt..kt+7): per kt two x4 at byte offs kt*128+{0,16}.
__device__ __forceinline__ void load16_tagged(const u32* p, i32x4 f[16]) {
  asm volatile(
      "global_load_dwordx4 %0, %16, off sc0 sc1\n\t"
      "global_load_dwordx4 %1, %16, off offset:16 sc0 sc1\n\t"
      "global_load_dwordx4 %2, %16, off offset:128 sc0 sc1\n\t"
      "global_load_dwordx4 %3, %16, off offset:144 sc0 sc1\n\t"
      "global_load_dwordx4 %4, %16, off offset:256 sc0 sc1\n\t"
      "global_load_dwordx4 %5, %16, off offset:272 sc0 sc1\n\t"
      "global_load_dwordx4 %6, %16, off offset:384 sc0 sc1\n\t"
      "global_load_dwordx4 %7, %16, off offset:400 sc0 sc1\n\t"
      "global_load_dwordx4 %8, %16, off offset:512 sc0 sc1\n\t"
      "global_load_dwordx4 %9, %16, off offset:528 sc0 sc1\n\t"
      "global_load_dwordx4 %10, %16, off offset:640 sc0 sc1\n\t"
      "global_load_dwordx4 %11, %16, off offset:656 sc0 sc1\n\t"
      "global_load_dwordx4 %12, %16, off offset:768 sc0 sc1\n\t"
      "global_load_dwordx4 %13, %16, off offset:784 sc0 sc1\n\t"
      "global_load_dwordx4 %14, %16, off offset:896 sc0 sc1\n\t"
      "global_load_dwordx4 %15, %16, off offset:912 sc0 sc1"
      : "=&v"(f[0]), "=&v"(f[1]), "=&v"(f[2]), "=&v"(f[3]),
        "=&v"(f[4]), "=&v"(f[5]), "=&v"(f[6]), "=&v"(f[7]),
        "=&v"(f[8]), "=&v"(f[9]), "=&v"(f[10]), "=&v"(f[11]),
        "=&v"(f[12]), "=&v"(f[13]), "=&v"(f[14]), "=&v"(f[15])
      : "v"(p) : "memory");
}

#define MFMA16(a, b, c) __builtin_amdgcn_mfma_f32_16x16x32_bf16((a), (b), (c), 0, 0, 0)

// One layer. in_ptr: L0 ? const float* x [B,T,64] : const u32* tagged seq [T,B,512].
// out_seq: tagged u32 [T,B,512]. tagbase = layer*256 + 1.
template <bool L0>
__global__ __launch_bounds__(256, 1)
void rec_kernel(const void* __restrict__ in_ptr, u32* __restrict__ out_seq,
                const float* __restrict__ Wx, const float* __restrict__ Wh,
                const float* __restrict__ bias, u32 tagbase) {
  constexpr int KIN = L0 ? N_D : N_H;
  const int i    = blockIdx.x >> 3;   // batch group 0..15
  const int j    = blockIdx.x & 7;    // col group 0..7
  const int tid  = threadIdx.x;
  const int lane = tid & 63;
  const int w    = tid >> 6;          // wave 0..3 -> 16-col tile
  const int quad = lane >> 4;
  const int l16  = lane & 15;
  const int nl   = w * 16 + l16;      // local col 0..63

  __shared__ u16   WhT[WCOLS][N_H];   // [n][k], k rotated by 8*n
  __shared__ u16   WxT[WCOLS][KIN];
  __shared__ float bsh[WCOLS];

  for (int e = tid; e < WCOLS * N_H; e += 256) {
    int n = e & 63, k = e >> 6;
    WhT[n][(k + 8 * n) & (N_H - 1)] = f2bf(Wh[k * N_H + j * WCOLS + n]);
  }
  for (int e = tid; e < WCOLS * KIN; e += 256) {
    int n = e & 63, k = e >> 6;
    WxT[n][(k + 8 * n) & (KIN - 1)] = f2bf(Wx[k * N_H + j * WCOLS + n]);
  }
  if (tid < WCOLS) bsh[tid] = bias[j * WCOLS + tid];
  __syncthreads();  // the ONLY barrier in the kernel

  const int arow = i * BC + l16;      // A-row this lane reads
  const float bval = bsh[nl];
  bool dead = false; (void)dead;

  for (int t = 0; t < N_T; ++t) {
    // ---- input projection (independent of recurrence) ----
    f32x4 p0 = {0.f, 0.f, 0.f, 0.f}, p1 = {0.f, 0.f, 0.f, 0.f};
    if (L0) {
      const float* xp = (const float*)in_ptr + ((size_t)arow * N_T + t) * N_D + quad * 8;
      p0 = MFMA16(cvt8(xp),      ld8(&WxT[nl][(quad * 8 + 8 * nl) & (KIN - 1)]), p0);
      p1 = MFMA16(cvt8(xp + 32), ld8(&WxT[nl][(32 + quad * 8 + 8 * nl) & (KIN - 1)]), p1);
    } else {
      // prev layer's tagged seq: complete at kernel boundary -> plain loads, no check
      const u32* sp = (const u32*)in_ptr + ((size_t)t * N_B + arow) * N_H + quad * 8;
#pragma unroll
      for (int kt = 0; kt < 16; kt += 2) {
        i32x4 q0 = *(const i32x4*)(sp + kt * 32);
        i32x4 q1 = *(const i32x4*)(sp + kt * 32 + 4);
        i32x4 q2 = *(const i32x4*)(sp + kt * 32 + 32);
        i32x4 q3 = *(const i32x4*)(sp + kt * 32 + 36);
        p0 = MFMA16(unpack_frag(q0, q1),
                    ld8(&WxT[nl][(kt * 32 + quad * 8 + 8 * nl) & (KIN - 1)]), p0);
        p1 = MFMA16(unpack_frag(q2, q3),
                    ld8(&WxT[nl][((kt + 1) * 32 + quad * 8 + 8 * nl) & (KIN - 1)]), p1);
      }
    }

    // ---- recurrent h_{t-1}@Wh: tagged retry loads ----
    f32x4 r0 = {0.f, 0.f, 0.f, 0.f}, r1 = {0.f, 0.f, 0.f, 0.f};
    if (t > 0) {
      const u32* ap = out_seq + ((size_t)(t - 1) * N_B + arow) * N_H + quad * 8;
      const u32 tag = tagbase + (u32)(t - 1);
      i32x4 fA[16], fB[16];
      u32 tries = 0;
      for (;;) {
        load16_tagged(ap, fA);
        load16_tagged(ap + 256, fB);
        asm volatile("s_waitcnt vmcnt(0)" ::: "memory");
        u32 bad = 0;
#pragma unroll
        for (int q = 0; q < 16; ++q) {
          bad |= ((u32)fA[q][0] ^ tag); bad |= ((u32)fA[q][1] ^ tag);
          bad |= ((u32)fA[q][2] ^ tag); bad |= ((u32)fA[q][3] ^ tag);
          bad |= ((u32)fB[q][0] ^ tag); bad |= ((u32)fB[q][1] ^ tag);
          bad |= ((u32)fB[q][2] ^ tag); bad |= ((u32)fB[q][3] ^ tag);
        }
        if (!__any((int)(bad & 0xFFFFu))) break;              // all tags fresh
        if (++tries > (1u << 20)) { dead = true; break; }     // loud fail, no hang
        if (tries > 16) __builtin_amdgcn_s_sleep(1);
      }
#pragma unroll
      for (int h = 0; h < 8; ++h) {
        r0 = MFMA16(unpack_frag(fA[2 * h], fA[2 * h + 1]),
                    ld8(&WhT[nl][(h * 32 + quad * 8 + 8 * nl) & (N_H - 1)]), r0);
      }
#pragma unroll
      for (int h = 0; h < 8; ++h) {
        r1 = MFMA16(unpack_frag(fB[2 * h], fB[2 * h + 1]),
                    ld8(&WhT[nl][((h + 8) * 32 + quad * 8 + 8 * nl) & (N_H - 1)]), r1);
      }
    }

    // ---- combine + tanh + tagged publish (C: col=l16 of tile, row=quad*4+r) ----
    const u32 wtag = tagbase + (u32)t;
    u32* drow = out_seq + ((size_t)t * N_B + i * BC + quad * 4) * N_H + j * WCOLS + nl;
#pragma unroll
    for (int r = 0; r < 4; ++r) {
      float u = p0[r] + p1[r] + r0[r] + r1[r] + bval;
      u32 word = ((u32)f2bf(fast_tanh(u)) << 16) | wtag;
      asm volatile("global_store_dword %0, %1, off sc0 sc1"
                   :: "v"(drow + (size_t)r * N_H), "v"(word) : "memory");
    }
    // no waitcnt, no barrier: tags make the stores self-publishing
  }
}

// out[b] = h2[T-1][b][:] . Wf + bf   (seq2 is tagged u32)
__global__ void head_kernel(const u32* __restrict__ seq2, const float* __restrict__ Wf,
                            const float* __restrict__ bf, float* __restrict__ out) {
  int b    = blockIdx.x;
  int lane = threadIdx.x;  // 64
  const u32* hrow = seq2 + ((size_t)(N_T - 1) * N_B + b) * N_H;
  float s = 0.f;
#pragma unroll
  for (int r = 0; r < N_H / 64; ++r) {
    int idx = lane * 8 + r;
    s += bf2f((u16)(hrow[idx] >> 16)) * Wf[idx];
  }
#pragma unroll
  for (int off = 32; off > 0; off >>= 1) s += __shfl_down(s, off);
  if (lane == 0) out[b] = s + bf[0];
}

extern "C" void kernel_launch(void* const* d_in, const int* in_sizes, int n_in,
                              void* d_out, int out_size, void* d_ws, size_t ws_size,
                              hipStream_t stream) {
  const float* x   = (const float*)d_in[0];
  const float* Wx0 = (const float*)d_in[1];
  const float* Wh0 = (const float*)d_in[2];
  const float* b0  = (const float*)d_in[3];
  const float* Wx1 = (const float*)d_in[4];
  const float* Wh1 = (const float*)d_in[5];
  const float* b1  = (const float*)d_in[6];
  const float* Wx2 = (const float*)d_in[7];
  const float* Wh2 = (const float*)d_in[8];
  const float* b2  = (const float*)d_in[9];
  const float* Wf  = (const float*)d_in[10];
  const float* bf  = (const float*)d_in[11];
  float* out = (float*)d_out;

  const size_t SEQ_BYTES = (size_t)N_T * N_B * N_H * sizeof(u32);  // 134,217,728
  if (ws_size < 2 * SEQ_BYTES) return;  // loud fail -> tells us ws_size budget

  char* ws  = (char*)d_ws;
  u32* seqA = (u32*)(ws);               // L0 (tags 1..256), then L2 (tags 513..768)
  u32* seqB = (u32*)(ws + SEQ_BYTES);   // L1 (tags 257..512)

  rec_kernel<true ><<<GBg * CG, 256, 0, stream>>>((const void*)x,    seqA, Wx0, Wh0, b0, 1u);
  rec_kernel<false><<<GBg * CG, 256, 0, stream>>>((const void*)seqA, seqB, Wx1, Wh1, b1, 257u);
  rec_kernel<false><<<GBg * CG, 256, 0, stream>>>((const void*)seqB, seqA, Wx2, Wh2, b2, 513u);
  head_kernel<<<N_B, 64, 0, stream>>>(seqA, Wf, bf, out);
}

// Round 6
// 2462.814 us; speedup vs baseline: 3.0053x; 3.0053x over previous
//
#include <hip/hip_runtime.h>

// ---------------------------------------------------------------------------
// RNN_69526930588180: 3-layer SimpleRNN (tanh), B=256, T=256, D=64, H=512.
//
// Round 6 = round 4 with the fast-path coherence bug fixed:
//  * fast-path h stores are now sc0 WRITE-THROUGH to L2 (round 4 used plain
//    write-back stores -> vmcnt(0) didn't imply L2 visibility -> stale reads).
//  * fast-path counter polls are atomic-RMW reads (global_atomic_add +0, sc0
//    return-old): execute at the line's coherence point, can't see stale
//    cached copies regardless of where counter atomics execute.
//  * handshake mask/count reads also RMW (one-time).
// Slow path (any-XCD placement) is bit-identical to the round-2 protocol that
// passed at 3155 us. Fast path engages only if a batch-group's 16 WGs verify
// (via HW_REG_XCC_ID handshake) that they share one XCD.
// ---------------------------------------------------------------------------

typedef unsigned short u16;
typedef unsigned int   u32;

typedef __attribute__((ext_vector_type(8))) short short8;
typedef __attribute__((ext_vector_type(4))) float f32x4;
typedef __attribute__((ext_vector_type(4))) int   i32x4;

#define N_B 256
#define N_T 256
#define N_D 64
#define N_H 512
#define GB  16   // batch groups
#define GC  16   // column groups
#define BC  16   // rows per group
#define HC  32   // cols per WG
#define CNT_TARGET 64  // 16 WGs x 4 waves publish per step

__device__ __forceinline__ u16 f2bf(float f) {
  union { float f; u32 u; } v; v.f = f;
  u32 u = v.u;
  u += 0x7fffu + ((u >> 16) & 1u);   // RNE
  return (u16)(u >> 16);
}
__device__ __forceinline__ float bf2f(u16 h) {
  union { u32 u; float f; } v; v.u = ((u32)h) << 16;
  return v.f;
}
__device__ __forceinline__ short8 ld8(const u16* p) { return *(const short8*)p; }
__device__ __forceinline__ short8 cvt8(const float* p) {
  short8 r;
#pragma unroll
  for (int j = 0; j < 8; ++j) r[j] = (short)f2bf(p[j]);
  return r;
}
__device__ __forceinline__ short8 as_s8(i32x4 v) {
  union { i32x4 i; short8 s; } u; u.i = v; return u.s;
}
// tanh(x) = 1 - 2/(exp(2x)+1); clamp (saturated anyway) to avoid inf.
__device__ __forceinline__ float fast_tanh(float x) {
  float xc = fminf(fmaxf(x, -9.f), 9.f);
  float e  = __builtin_amdgcn_exp2f(xc * 2.8853900817779268f);  // exp2(2x*log2e)
  return 1.f - 2.f * __builtin_amdgcn_rcpf(e + 1.f);
}
// Atomic-RMW read (add 0, return old): executes at the line's coherence point.
__device__ __forceinline__ u32 rmw_read(u32* p) {
  u32 v, z = 0;
  asm volatile("global_atomic_add %0, %1, %2, off sc0\n\ts_waitcnt vmcnt(0)"
               : "=v"(v) : "v"(p), "v"(z) : "memory");
  return v;
}

// 16 batched A-fragment loads (row fixed, k = kt*32 + quad*8), one vmcnt.
__device__ __forceinline__ void load_frags16_fast(const u16* p, i32x4 f[16]) {
  asm volatile(
      "global_load_dwordx4 %0, %16, off sc0\n\t"
      "global_load_dwordx4 %1, %16, off offset:64 sc0\n\t"
      "global_load_dwordx4 %2, %16, off offset:128 sc0\n\t"
      "global_load_dwordx4 %3, %16, off offset:192 sc0\n\t"
      "global_load_dwordx4 %4, %16, off offset:256 sc0\n\t"
      "global_load_dwordx4 %5, %16, off offset:320 sc0\n\t"
      "global_load_dwordx4 %6, %16, off offset:384 sc0\n\t"
      "global_load_dwordx4 %7, %16, off offset:448 sc0\n\t"
      "global_load_dwordx4 %8, %16, off offset:512 sc0\n\t"
      "global_load_dwordx4 %9, %16, off offset:576 sc0\n\t"
      "global_load_dwordx4 %10, %16, off offset:640 sc0\n\t"
      "global_load_dwordx4 %11, %16, off offset:704 sc0\n\t"
      "global_load_dwordx4 %12, %16, off offset:768 sc0\n\t"
      "global_load_dwordx4 %13, %16, off offset:832 sc0\n\t"
      "global_load_dwordx4 %14, %16, off offset:896 sc0\n\t"
      "global_load_dwordx4 %15, %16, off offset:960 sc0\n\t"
      "s_waitcnt vmcnt(0)"
      : "=&v"(f[0]), "=&v"(f[1]), "=&v"(f[2]), "=&v"(f[3]),
        "=&v"(f[4]), "=&v"(f[5]), "=&v"(f[6]), "=&v"(f[7]),
        "=&v"(f[8]), "=&v"(f[9]), "=&v"(f[10]), "=&v"(f[11]),
        "=&v"(f[12]), "=&v"(f[13]), "=&v"(f[14]), "=&v"(f[15])
      : "v"(p) : "memory");
}
__device__ __forceinline__ void load_frags16_slow(const u16* p, i32x4 f[16]) {
  asm volatile(
      "global_load_dwordx4 %0, %16, off sc0 sc1\n\t"
      "global_load_dwordx4 %1, %16, off offset:64 sc0 sc1\n\t"
      "global_load_dwordx4 %2, %16, off offset:128 sc0 sc1\n\t"
      "global_load_dwordx4 %3, %16, off offset:192 sc0 sc1\n\t"
      "global_load_dwordx4 %4, %16, off offset:256 sc0 sc1\n\t"
      "global_load_dwordx4 %5, %16, off offset:320 sc0 sc1\n\t"
      "global_load_dwordx4 %6, %16, off offset:384 sc0 sc1\n\t"
      "global_load_dwordx4 %7, %16, off offset:448 sc0 sc1\n\t"
      "global_load_dwordx4 %8, %16, off offset:512 sc0 sc1\n\t"
      "global_load_dwordx4 %9, %16, off offset:576 sc0 sc1\n\t"
      "global_load_dwordx4 %10, %16, off offset:640 sc0 sc1\n\t"
      "global_load_dwordx4 %11, %16, off offset:704 sc0 sc1\n\t"
      "global_load_dwordx4 %12, %16, off offset:768 sc0 sc1\n\t"
      "global_load_dwordx4 %13, %16, off offset:832 sc0 sc1\n\t"
      "global_load_dwordx4 %14, %16, off offset:896 sc0 sc1\n\t"
      "global_load_dwordx4 %15, %16, off offset:960 sc0 sc1\n\t"
      "s_waitcnt vmcnt(0)"
      : "=&v"(f[0]), "=&v"(f[1]), "=&v"(f[2]), "=&v"(f[3]),
        "=&v"(f[4]), "=&v"(f[5]), "=&v"(f[6]), "=&v"(f[7]),
        "=&v"(f[8]), "=&v"(f[9]), "=&v"(f[10]), "=&v"(f[11]),
        "=&v"(f[12]), "=&v"(f[13]), "=&v"(f[14]), "=&v"(f[15])
      : "v"(p) : "memory");
}

// One layer. in_ptr: L0 ? const float* x [B,T,64] : const u16* seq_in [T,B,512].
// out_seq: u16 [T,B,512]. cnt: GB*N_T counters. hsk: 2*GB (arrive, mask).
template <bool L0>
__global__ __launch_bounds__(256, 1)
void rec_kernel(const void* __restrict__ in_ptr, u16* __restrict__ out_seq,
                const float* __restrict__ Wx, const float* __restrict__ Wh,
                const float* __restrict__ bias, u32* __restrict__ cnt,
                u32* __restrict__ hsk) {
  constexpr int KIN = L0 ? N_D : N_H;
  // Swizzle: bg's 16 WGs share blockIdx%8 (expected XCD under %8 round-robin).
  const int c8   = blockIdx.x & 7;
  const int s    = blockIdx.x >> 3;         // 0..31
  const int i    = c8 + 8 * (s >> 4);       // batch group 0..15
  const int j    = s & 15;                  // column group 0..15
  const int tid  = threadIdx.x;
  const int lane = tid & 63;
  const int w    = tid >> 6;
  const int quad = lane >> 4;
  const int l16  = lane & 15;
  const int gemm = w >> 1;            // 0: recurrent h@Wh (waves 0-1), 1: input proj
  const int nt   = w & 1;
  const int n_local = nt * 16 + l16;

  __shared__ u16   WhT[HC][N_H];      // [n][k], k rotated by 8*n
  __shared__ u16   WxT[HC][KIN];
  __shared__ float bsh[HC];
  __shared__ float Cbuf[2][16][33];

  // ---- startup handshake: are all 16 WGs of bg i on one XCD? ----
  u32 xcc;
  asm volatile("s_getreg_b32 %0, hwreg(HW_REG_XCC_ID)" : "=s"(xcc));
  if (tid == 0) {
    __hip_atomic_fetch_or(&hsk[GB + i], 1u << (xcc & 7), __ATOMIC_RELAXED,
                          __HIP_MEMORY_SCOPE_AGENT);
    asm volatile("s_waitcnt vmcnt(0)" ::: "memory");  // or acked before count
    __hip_atomic_fetch_add(&hsk[i], 1u, __ATOMIC_RELAXED,
                           __HIP_MEMORY_SCOPE_AGENT);
  }

  // Stage weight slices while the handshake propagates.
  for (int e = tid; e < HC * N_H; e += 256) {
    int n = e & 31, k = e >> 5;
    WhT[n][(k + 8 * n) & (N_H - 1)] = f2bf(Wh[k * N_H + j * HC + n]);
  }
  for (int e = tid; e < HC * KIN; e += 256) {
    int n = e & 31, k = e >> 5;
    WxT[n][(k + 8 * n) & (KIN - 1)] = f2bf(Wx[k * N_H + j * HC + n]);
  }
  if (tid < HC) bsh[tid] = bias[j * HC + tid];

  bool fast = false;
  if (tid == 0) {
    u32 it = 0;
    while (rmw_read(&hsk[i]) < (u32)GC) {
      __builtin_amdgcn_s_sleep(1);
      if (++it > (1u << 22)) break;
    }
    if (it <= (1u << 22)) {
      u32 m = rmw_read(&hsk[GB + i]);
      fast = (m != 0u) && ((m & (m - 1u)) == 0u);
    }
    ((volatile u32*)bsh)[HC - 1] = fast ? 1u : 0u;  // stash via LDS temporarily
  }
  __syncthreads();
  {
    u32 fv = ((volatile u32*)bsh)[HC - 1];
    fast = (fv == 1u);
  }
  __syncthreads();
  if (tid == 0) bsh[HC - 1] = bias[j * HC + HC - 1];  // restore clobbered bias
  __syncthreads();

  bool dead = false;

  for (int t = 0; t < N_T; ++t) {
    f32x4 acc = {0.f, 0.f, 0.f, 0.f};

    if (gemm == 1) {
      // ---- input projection (off critical path) ----
      f32x4 a0 = {0.f, 0.f, 0.f, 0.f}, a1 = {0.f, 0.f, 0.f, 0.f};
      if (L0) {
        const float* xp = (const float*)in_ptr +
            ((size_t)(i * BC + l16) * N_T + t) * N_D + quad * 8;
        short8 f0 = cvt8(xp), f1 = cvt8(xp + 32);
        a0 = __builtin_amdgcn_mfma_f32_16x16x32_bf16(
            f0, ld8(&WxT[n_local][(quad * 8 + 8 * n_local) & (KIN - 1)]), a0, 0, 0, 0);
        a1 = __builtin_amdgcn_mfma_f32_16x16x32_bf16(
            f1, ld8(&WxT[n_local][(32 + quad * 8 + 8 * n_local) & (KIN - 1)]), a1, 0, 0, 0);
      } else {
        const u16* sp = (const u16*)in_ptr +
            ((size_t)t * N_B + i * BC + l16) * N_H + quad * 8;
#pragma unroll
        for (int kt = 0; kt < KIN / 32; kt += 2) {
          a0 = __builtin_amdgcn_mfma_f32_16x16x32_bf16(
              ld8(sp + kt * 32),
              ld8(&WxT[n_local][(kt * 32 + quad * 8 + 8 * n_local) & (KIN - 1)]), a0, 0, 0, 0);
          a1 = __builtin_amdgcn_mfma_f32_16x16x32_bf16(
              ld8(sp + (kt + 1) * 32),
              ld8(&WxT[n_local][((kt + 1) * 32 + quad * 8 + 8 * n_local) & (KIN - 1)]), a1, 0, 0, 0);
        }
      }
#pragma unroll
      for (int e = 0; e < 4; ++e) acc[e] = a0[e] + a1[e];
      int rowb = quad * 4;
      Cbuf[1][rowb + 0][n_local] = acc[0];
      Cbuf[1][rowb + 1][n_local] = acc[1];
      Cbuf[1][rowb + 2][n_local] = acc[2];
      Cbuf[1][rowb + 3][n_local] = acc[3];
    } else {
      // ---- recurrent h_{t-1}@Wh ----
      if (t > 0) {
        // Wave-level wait: lane 0 polls; one PC per wave parks the rest.
        if (lane == 0 && !dead) {
          u32* cp = &cnt[i * N_T + (t - 1)];
          u32 it = 0;
          for (;;) {
            u32 v;
            if (fast) {
              v = rmw_read(cp);  // RMW read: coherent wherever the line lives
            } else {
              v = __hip_atomic_load(cp, __ATOMIC_RELAXED, __HIP_MEMORY_SCOPE_AGENT);
            }
            if (v >= (u32)CNT_TARGET) break;
            __builtin_amdgcn_s_sleep(1);
            if (++it > (1u << 22)) { dead = true; break; }
          }
        }
        const u16* ap = out_seq +
            ((size_t)(t - 1) * N_B + i * BC + l16) * N_H + quad * 8;
        i32x4 fr[16];
        if (fast) load_frags16_fast(ap, fr);
        else      load_frags16_slow(ap, fr);
        f32x4 a0 = {0.f, 0.f, 0.f, 0.f}, a1 = {0.f, 0.f, 0.f, 0.f};
#pragma unroll
        for (int kt = 0; kt < 16; kt += 2) {
          a0 = __builtin_amdgcn_mfma_f32_16x16x32_bf16(
              as_s8(fr[kt]),
              ld8(&WhT[n_local][(kt * 32 + quad * 8 + 8 * n_local) & (N_H - 1)]), a0, 0, 0, 0);
          a1 = __builtin_amdgcn_mfma_f32_16x16x32_bf16(
              as_s8(fr[kt + 1]),
              ld8(&WhT[n_local][((kt + 1) * 32 + quad * 8 + 8 * n_local) & (N_H - 1)]), a1, 0, 0, 0);
        }
#pragma unroll
        for (int e = 0; e < 4; ++e) acc[e] = a0[e] + a1[e];
      }
      int rowb = quad * 4;
      Cbuf[0][rowb + 0][n_local] = acc[0];
      Cbuf[0][rowb + 1][n_local] = acc[1];
      Cbuf[0][rowb + 2][n_local] = acc[2];
      Cbuf[0][rowb + 3][n_local] = acc[3];
    }

    __syncthreads();  // both Cbuf halves complete

    // ---- combine: u = h@Wh + x@Wx + b; h = tanh(u); publish ----
    {
      int r   = tid >> 4;
      int c0i = (tid & 15) * 2;
      float u0 = Cbuf[0][r][c0i]     + Cbuf[1][r][c0i]     + bsh[c0i];
      float u1 = Cbuf[0][r][c0i + 1] + Cbuf[1][r][c0i + 1] + bsh[c0i + 1];
      u32 pk = (u32)f2bf(fast_tanh(u0)) | ((u32)f2bf(fast_tanh(u1)) << 16);
      u32* dst = (u32*)&out_seq[((size_t)t * N_B + i * BC + r) * N_H + j * HC + c0i];
      if (fast) {
        // sc0 write-through: vmcnt(0) then implies L2 (XCD coherence point) ack.
        asm volatile("global_store_dword %0, %1, off sc0" :: "v"(dst), "v"(pk) : "memory");
      } else {
        asm volatile("global_store_dword %0, %1, off sc0 sc1" :: "v"(dst), "v"(pk) : "memory");
      }
    }
    asm volatile("s_waitcnt vmcnt(0)" ::: "memory");  // stores acked at L2/LLC
    if (lane == 0) {
      u32* cp = &cnt[i * N_T + t];
      if (fast) {
        u32 one = 1u;
        asm volatile("global_atomic_add %0, %1, off" :: "v"(cp), "v"(one) : "memory");
      } else {
        __hip_atomic_fetch_add(cp, 1u, __ATOMIC_RELAXED, __HIP_MEMORY_SCOPE_AGENT);
      }
    }

    __syncthreads();  // combine reads done before next-iter Cbuf writes
  }
}

// out[b] = seq2[T-1][b][:] . Wf + bf
__global__ void head_kernel(const u16* __restrict__ seq2, const float* __restrict__ Wf,
                            const float* __restrict__ bf, float* __restrict__ out) {
  int b    = blockIdx.x;
  int lane = threadIdx.x;  // 64
  const u16* hrow = seq2 + ((size_t)(N_T - 1) * N_B + b) * N_H;
  float s = 0.f;
#pragma unroll
  for (int r = 0; r < N_H / 64; ++r) {
    int idx = lane * 8 + r;
    s += bf2f(hrow[idx]) * Wf[idx];
  }
#pragma unroll
  for (int off = 32; off > 0; off >>= 1) s += __shfl_down(s, off);
  if (lane == 0) out[b] = s + bf[0];
}

extern "C" void kernel_launch(void* const* d_in, const int* in_sizes, int n_in,
                              void* d_out, int out_size, void* d_ws, size_t ws_size,
                              hipStream_t stream) {
  const float* x   = (const float*)d_in[0];
  const float* Wx0 = (const float*)d_in[1];
  const float* Wh0 = (const float*)d_in[2];
  const float* b0  = (const float*)d_in[3];
  const float* Wx1 = (const float*)d_in[4];
  const float* Wh1 = (const float*)d_in[5];
  const float* b1  = (const float*)d_in[6];
  const float* Wx2 = (const float*)d_in[7];
  const float* Wh2 = (const float*)d_in[8];
  const float* b2  = (const float*)d_in[9];
  const float* Wf  = (const float*)d_in[10];
  const float* bf  = (const float*)d_in[11];
  float* out = (float*)d_out;

  const size_t SEQ_BYTES = (size_t)N_T * N_B * N_H * sizeof(u16);  // 67,108,864
  const size_t CNT_U32   = (size_t)3 * GB * N_T;                   // 12,288
  const size_t HSK_U32   = (size_t)3 * 2 * GB;                     // 96
  if (ws_size < 2 * SEQ_BYTES + (CNT_U32 + HSK_U32) * sizeof(u32)) return;

  char* ws  = (char*)d_ws;
  u16* seqA = (u16*)(ws);
  u16* seqB = (u16*)(ws + SEQ_BYTES);
  u32* cnt  = (u32*)(ws + 2 * SEQ_BYTES);
  u32* hsk  = cnt + CNT_U32;

  (void)hipMemsetAsync(cnt, 0, (CNT_U32 + HSK_U32) * sizeof(u32), stream);

  rec_kernel<true ><<<256, 256, 0, stream>>>((const void*)x,    seqA, Wx0, Wh0, b0,
                                             cnt,              hsk);
  rec_kernel<false><<<256, 256, 0, stream>>>((const void*)seqA, seqB, Wx1, Wh1, b1,
                                             cnt + GB * N_T,   hsk + 2 * GB);
  rec_kernel<false><<<256, 256, 0, stream>>>((const void*)seqB, seqA, Wx2, Wh2, b2,
                                             cnt + 2 * GB * N_T, hsk + 4 * GB);
  head_kernel<<<N_B, 64, 0, stream>>>(seqA, Wf, bf, out);
}